// Round 3
// baseline (280.525 us; speedup 1.0000x reference)
//
#include <hip/hip_runtime.h>
#include <stdint.h>

// BitLinear via i8 MFMA, round 7.
//
// Post-mortem r6: counted-vmcnt deep pipeline changed NOTHING (143 us,
// MfmaUtil 43%) -> the barrier drain was never the cost. Arithmetic:
// per K-step per CU, MFMA = 1170 cyc but LDS reads = 96 KB ~ 860 cyc at
// the ~112 B/cyc effective LDS BW, plus ~650 cyc staging/barrier bubbles;
// measured 2680 cyc/step == near-full serialization. LDS READ TRAFFIC is
// the co-bottleneck.
//
// Change r7: A operand bypasses LDS entirely. Each wave loads its own A
// fragments global->VGPR (8 x dwordx4 per step, double-buffered regs,
// 1-step prefetch ~1200 cyc >> L2 latency; the 4 waves sharing a wave-row
// re-read the same 8 KB -> L1-served). Only W is staged via
// global_load_lds (2 x 16 KB buffers). Per-CU LDS-read/step: 96 -> 32 KB.
// acc(128) + 2x32 A-regs + addr ~ 220 VGPR -> still 2 waves/SIMD.
//
// Blocked layout (unchanged): byte (m,k) ->
//   group g=m>>5 at g*131072; k-block kb=k>>5 at kb*1024; lane-order inside.
// One 1-KB block = one 32x32 i8 MFMA fragment in lane order.

typedef int v4i  __attribute__((ext_vector_type(4)));
typedef int v16i __attribute__((ext_vector_type(16)));

#define BATCH 8192
#define OUTF  4096
#define KDIM  4096
#define BM    256
#define BN    256
#define BKB   64
#define NSTEP (KDIM / BKB)   // 64

// ---------------- unpack: packed bits -> +/-1 int8, blocked layout ----------
// x holds 8 valid bits. byte j of pl = (bit j) ? 0x01 : 0xFF, ph = bits 4..7.
__device__ __forceinline__ void expand_word(uint32_t x, uint32_t& pl, uint32_t& ph) {
    uint32_t lo = ((x & 0xFu) * 0x204081u) & 0x01010101u;          // bit j -> byte j
    uint32_t hi = (((x >> 4) & 0xFu) * 0x204081u) & 0x01010101u;
    pl = ~((lo << 8) - (lo << 1));   // ~(lo*0xFE): 1 -> 0x01, 0 -> 0xFF per byte
    ph = ~((hi << 8) - (hi << 1));
}

__global__ __launch_bounds__(256) void unpack_kernel(const int* __restrict__ a_packed,
                                                     const int* __restrict__ w_packed,
                                                     char* __restrict__ Ai8,
                                                     char* __restrict__ Wi8) {
    const int A_WORK = BATCH * 32;               // one thread per (row, 128-B chunk)
    int t = blockIdx.x * 256 + threadIdx.x;
    const int* __restrict__ src = a_packed;
    int4* dst = (int4*)Ai8;
    if (t >= A_WORK) { t -= A_WORK; src = w_packed; dst = (int4*)Wi8; }

    const int r = t & 31;          // row within group (lanes 0..31 -> coalesced writes)
    const int c = (t >> 5) & 31;   // 128-B k-chunk
    const int g = t >> 10;         // row group
    const int m = g * 32 + r;

    // 64 contiguous bytes: words m*512 + c*16 .. +15  (4 x global_load_dwordx4)
    const int4* s4 = (const int4*)src + (m * 128 + c * 4);
    int4 v0 = s4[0], v1 = s4[1], v2 = s4[2], v3 = s4[3];

    int4* dbase = dst + ((g * 32 + c) * 256 + r);

#define EMIT(S, V)                                                     \
    {                                                                  \
        uint32_t l0, h0, l1, h1, l2, h2, l3, h3;                       \
        expand_word((uint32_t)(V).x, l0, h0);                          \
        expand_word((uint32_t)(V).y, l1, h1);                          \
        expand_word((uint32_t)(V).z, l2, h2);                          \
        expand_word((uint32_t)(V).w, l3, h3);                          \
        int4 o0 = make_int4((int)l0, (int)h0, (int)l1, (int)h1);       \
        int4 o1 = make_int4((int)l2, (int)h2, (int)l3, (int)h3);       \
        dbase[(S) * 64]      = o0;  /* half 0 */                       \
        dbase[(S) * 64 + 32] = o1;  /* half 1 */                       \
    }
    EMIT(0, v0) EMIT(1, v1) EMIT(2, v2) EMIT(3, v3)
#undef EMIT
}

// ------- i8 MFMA GEMM: 256x256 tile, 8 waves, A in regs, W via LDS ---------
__global__ __launch_bounds__(512, 2) void bitgemm_mfma(const char* __restrict__ A,
                                                       const char* __restrict__ W,
                                                       const float* __restrict__ bias,
                                                       float* __restrict__ out) {
    // W only: 2 buffers x 16 KB. Per buffer, block (g2*2+sl)*1024, g2=0..7.
    __shared__ __attribute__((aligned(16))) char lds[2 * 16384];

    const int tid  = threadIdx.x;
    const int lane = tid & 63;
    const int w    = __builtin_amdgcn_readfirstlane(tid >> 6);  // 0..7
    const int wr   = w >> 2;   // wave M row: 0..1  (128 rows each)
    const int wc   = w & 3;    // wave N col: 0..3  (64 cols each)
    const int bx   = blockIdx.x;   // N: 16 blocks
    const int by   = blockIdx.y;   // M: 32 blocks

    // group stride in blocked layout = 32 k-blocks * 4096 B = 131072 B
    // A: wave reads groups (by*8 + wr*4 + mt), mt = 0..3, straight to regs.
    const char* pAw = A + (size_t)(by * 8 + wr * 4) * 131072 + (size_t)lane * 16;
    // W: wave stages group (bx*8 + w), both k-subblocks, into LDS.
    const char* pWs = W + (size_t)(bx * 8 + w) * 131072 + (size_t)lane * 16;

    v16i acc[4][2];
#pragma unroll
    for (int mt = 0; mt < 4; ++mt)
#pragma unroll
        for (int nt = 0; nt < 2; ++nt)
#pragma unroll
            for (int rg = 0; rg < 16; ++rg) acc[mt][nt][rg] = 0;

    // load A fragments for k-step kc into a named register buffer
    auto loadA = [&](v4i (&dst)[4][2], int kc) {
#pragma unroll
        for (int mt = 0; mt < 4; ++mt)
#pragma unroll
            for (int sl = 0; sl < 2; ++sl)
                dst[mt][sl] = *(const v4i*)(pAw + mt * 131072 + (kc * 2 + sl) * 1024);
    };

    // stage W for k-step kc into lds buffer buf (2 x 1 KB per wave)
    auto stageW = [&](int kc, int buf) {
        char* ldst = lds + buf * 16384 + w * 2048;
#pragma unroll
        for (int sl = 0; sl < 2; ++sl)
            __builtin_amdgcn_global_load_lds(
                (const __attribute__((address_space(1))) void*)(pWs + (kc * 2 + sl) * 1024),
                (__attribute__((address_space(3))) void*)(ldst + sl * 1024),
                16, 0, 0);
    };

    // compute one k-step from a register A buffer + LDS W buffer
    auto compute = [&](const v4i (&av)[4][2], int buf) {
        const char* ldsC = lds + buf * 16384 + wc * 4096 + lane * 16;
#pragma unroll
        for (int sl = 0; sl < 2; ++sl) {
            v4i wv0 = *(const v4i*)(ldsC + sl * 1024);          // nt=0: block (wc*2)*2+sl
            v4i wv1 = *(const v4i*)(ldsC + 2048 + sl * 1024);   // nt=1: block (wc*2+1)*2+sl
            __builtin_amdgcn_s_setprio(1);
#pragma unroll
            for (int mt = 0; mt < 4; ++mt) {
                acc[mt][0] = __builtin_amdgcn_mfma_i32_32x32x32_i8(av[mt][sl], wv0,
                                                                   acc[mt][0], 0, 0, 0);
                acc[mt][1] = __builtin_amdgcn_mfma_i32_32x32x32_i8(av[mt][sl], wv1,
                                                                   acc[mt][1], 0, 0, 0);
            }
            __builtin_amdgcn_s_setprio(0);
        }
    };

    v4i aA[4][2], aB[4][2];   // named double buffer (static indexing, rule #20)

    // Prologue: step 0 in flight.
    loadA(aA, 0);
    stageW(0, 0);

#pragma unroll 1
    for (int kc = 0; kc < NSTEP; kc += 2) {
        // syncthreads = s_waitcnt vmcnt(0) lgkmcnt(0) + s_barrier:
        // step-kc loads (issued one full compute phase ago) are done for ALL
        // waves, and all waves finished reading the buffer we overwrite next.
        __syncthreads();
        if (kc + 1 < NSTEP) { loadA(aB, kc + 1); stageW(kc + 1, 1); }
        compute(aA, 0);
        __syncthreads();
        if (kc + 2 < NSTEP) { loadA(aA, kc + 2); stageW(kc + 2, 0); }
        compute(aB, 1);
    }

    // Epilogue. C/D layout (32x32, HW-verified): col=lane&31,
    // row=(reg&3)+8*(reg>>2)+4*(lane>>5).
    const int cl = lane & 31;
    const int r0 = (lane >> 5) * 4;
    const int m0 = by * BM;
    const int n0 = bx * BN;
#pragma unroll
    for (int mt = 0; mt < 4; ++mt) {
        const int rowbase = m0 + (wr * 4 + mt) * 32 + r0;
#pragma unroll
        for (int nt = 0; nt < 2; ++nt) {
            const int col = n0 + (wc * 2 + nt) * 32 + cl;
            const float bv = bias[col];
#pragma unroll
            for (int rg = 0; rg < 16; ++rg) {
                const int row = rowbase + (rg & 3) + 8 * (rg >> 2);
                out[(size_t)row * OUTF + col] = (float)acc[mt][nt][rg] + bv;
            }
        }
    }
}

extern "C" void kernel_launch(void* const* d_in, const int* in_sizes, int n_in,
                              void* d_out, int out_size, void* d_ws, size_t ws_size,
                              hipStream_t stream) {
    const int*   a_packed = (const int*)d_in[0];    // [8192, 512]
    const int*   w_packed = (const int*)d_in[1];    // [4096, 512]
    const float* bias     = (const float*)d_in[2];  // [4096]
    float*       out      = (float*)d_out;          // [8192, 4096]

    char* Ai8 = (char*)d_ws;                         // 32 MiB blocked
    char* Wi8 = Ai8 + (size_t)BATCH * KDIM;          // 16 MiB blocked

    const int total = (BATCH + OUTF) * 32;           // 393,216 threads
    unpack_kernel<<<total / 256, 256, 0, stream>>>(a_packed, w_packed, Ai8, Wi8);

    dim3 grid(OUTF / BN, BATCH / BM);   // (16, 32)
    bitgemm_mfma<<<grid, 512, 0, stream>>>(Ai8, Wi8, bias, out);
}

// Round 5
// 259.151 us; speedup vs baseline: 1.0825x; 1.0825x over previous
//
#include <hip/hip_runtime.h>
#include <stdint.h>

// BitLinear via i8 MFMA, round 8 resubmit (round-4 bench was an infra
// failure: "MI355X container failed twice"; kernel re-audited, no defect).
//
// Post-mortem r6/r7: barrier/vmcnt pipelining (r6) changed nothing; A-in-regs
// of EXPANDED data (r7) regressed. The binding costs are (a) 96 KB/CU/step of
// LDS reads ~= the MFMA time itself, (b) the 48 MiB expanded intermediate.
// Both exist only because operands are materialized as +/-1 bytes.
//
// Round 8 removes the expansion from the memory system:
//   identity: for bits a,w in {0,1}:  sum (2a-1)(2w-1)
//           = 4*sum(a&w) - 2*rowsum(a) - 2*rowsum(w) + K
//   k1 bitpack: int32-per-byte input -> dense bit panels, PAIR-MAJOR:
//       A'[pair p][row m][16 B], W'[p][n][16 B]  (4 MiB + 2 MiB, L2-resident)
//   k2 fused GEMM: NO LDS, NO barriers. Each wave loads its rows' 16 B/pair
//       (fully coalesced), expands bits -> {0,1} bytes in regs (3 VALU per
//       4 bytes: (n*0x204081)&0x01010101, the verified spread), MFMAs
//       directly, accumulates __popc rowsums, applies the identity + bias in
//       the epilogue. Per SIMD per K-step: MFMA 1170 cyc vs VALU ~960 on
//       separate pipes; LDS pipe idle; packed loads ~14 B/cyc.
//
// Output mapping (32x32 i8 MFMA C/D, HW-verified, unchanged since r4):
//   col = lane&31, row = (reg&3) + 8*(reg>>2) + 4*(lane>>5).

typedef int v4i  __attribute__((ext_vector_type(4)));
typedef int v16i __attribute__((ext_vector_type(16)));

#define BATCH 8192
#define OUTF  4096
#define KDIM  4096
#define BM    256
#define BN    256
#define NPAIR 32   // 32 pairs; 1 pair = 128 k-bits = 16 B/row = 2 K-steps

// ---------------- k1: repack to dense bits, pair-major --------------------
__device__ __forceinline__ uint32_t pack4(int4 q) {
    // each int holds one byte (0..255) of packed bits, LSB-first along k
    return (uint32_t)q.x | ((uint32_t)q.y << 8) |
           ((uint32_t)q.z << 16) | ((uint32_t)q.w << 24);
}

__global__ __launch_bounds__(256) void bitpack(const int* __restrict__ ap,
                                               const int* __restrict__ wp,
                                               uint4* __restrict__ Ab,
                                               uint4* __restrict__ Wb) {
    int t = blockIdx.x * 256 + threadIdx.x;
    const int* src;
    uint4* dst;
    if (t < BATCH * NPAIR) {                 // A: 262144 threads
        const int p = t >> 13, m = t & 8191;
        src = ap + m * 512 + p * 16;
        dst = Ab + (p * BATCH + m);
    } else {                                 // W: 131072 threads
        const int u = t - BATCH * NPAIR;
        const int p = u >> 12, n = u & 4095;
        src = wp + n * 512 + p * 16;
        dst = Wb + (p * OUTF + n);
    }
    const int4* s4 = (const int4*)src;       // 64 B contiguous read
    int4 q0 = s4[0], q1 = s4[1], q2 = s4[2], q3 = s4[3];
    uint4 o;
    o.x = pack4(q0); o.y = pack4(q1); o.z = pack4(q2); o.w = pack4(q3);
    *dst = o;                                // 16 B coalesced write
}

// ---------------- k2: fused expand + i8 MFMA GEMM, no LDS ------------------
// bit j of nibble -> byte j, value {0,1}
__device__ __forceinline__ uint32_t spread4(uint32_t n) {
    return (n * 0x204081u) & 0x01010101u;
}
// 16 bits (LSB-first along k) -> 16 bytes of {0,1}
__device__ __forceinline__ v4i expand16(uint32_t x) {
    v4i r;
    r[0] = (int)spread4(x & 0xFu);
    r[1] = (int)spread4((x >> 4) & 0xFu);
    r[2] = (int)spread4((x >> 8) & 0xFu);
    r[3] = (int)spread4(x >> 12);            // x < 2^16, no mask needed
    return r;
}

__global__ __launch_bounds__(512, 2) void bitgemm_fused(const v4i* __restrict__ Ab,
                                                        const v4i* __restrict__ Wb,
                                                        const float* __restrict__ bias,
                                                        float* __restrict__ out) {
    const int tid  = threadIdx.x;
    const int lane = tid & 63;
    const int w    = __builtin_amdgcn_readfirstlane(tid >> 6);  // 0..7
    const int wr   = w >> 2;        // wave M row: 0..1 (128 rows)
    const int wc   = w & 3;         // wave N col: 0..3 (64 cols)
    const int rl   = lane & 31;
    const int hl16 = (lane >> 5) * 16;  // which 16-bit half this lane consumes
    const int bx   = blockIdx.x;    // N: 16
    const int by   = blockIdx.y;    // M: 32

    // lane's packed rows (pair-major panels)
    const int rowA0 = by * 256 + wr * 128 + rl;   // + mt*32
    const int rowW0 = bx * 256 + wc * 64 + rl;    // + nt*32

    v16i acc[4][2];
#pragma unroll
    for (int mt = 0; mt < 4; ++mt)
#pragma unroll
        for (int nt = 0; nt < 2; ++nt)
#pragma unroll
            for (int rg = 0; rg < 16; ++rg) acc[mt][nt][rg] = 0;

    int ars[4] = {0, 0, 0, 0};   // rowsum(A bits) for lane's 4 A rows
    int wrs[2] = {0, 0};         // rowsum(W bits) for lane's 2 W rows

    auto loadPair = [&](v4i (&pa)[4], v4i (&pw)[2], int p) {
#pragma unroll
        for (int mt = 0; mt < 4; ++mt)
            pa[mt] = Ab[(size_t)p * BATCH + rowA0 + mt * 32];
#pragma unroll
        for (int nt = 0; nt < 2; ++nt)
            pw[nt] = Wb[(size_t)p * OUTF + rowW0 + nt * 32];
    };

    auto computePair = [&](const v4i (&pa)[4], const v4i (&pw)[2]) {
#pragma unroll
        for (int mt = 0; mt < 4; ++mt)
            ars[mt] += __popc((uint32_t)pa[mt][0]) + __popc((uint32_t)pa[mt][1]) +
                       __popc((uint32_t)pa[mt][2]) + __popc((uint32_t)pa[mt][3]);
#pragma unroll
        for (int nt = 0; nt < 2; ++nt)
            wrs[nt] += __popc((uint32_t)pw[nt][0]) + __popc((uint32_t)pw[nt][1]) +
                       __popc((uint32_t)pw[nt][2]) + __popc((uint32_t)pw[nt][3]);
        // 4 x K=32 MFMA windows per pair: word c, 16-bit half = hl16
#pragma unroll
        for (int c = 0; c < 4; ++c) {
            v4i av[4], wv[2];
#pragma unroll
            for (int mt = 0; mt < 4; ++mt)
                av[mt] = expand16(((uint32_t)pa[mt][c] >> hl16) & 0xFFFFu);
#pragma unroll
            for (int nt = 0; nt < 2; ++nt)
                wv[nt] = expand16(((uint32_t)pw[nt][c] >> hl16) & 0xFFFFu);
            __builtin_amdgcn_s_setprio(1);
#pragma unroll
            for (int mt = 0; mt < 4; ++mt) {
                acc[mt][0] = __builtin_amdgcn_mfma_i32_32x32x32_i8(av[mt], wv[0],
                                                                   acc[mt][0], 0, 0, 0);
                acc[mt][1] = __builtin_amdgcn_mfma_i32_32x32x32_i8(av[mt], wv[1],
                                                                   acc[mt][1], 0, 0, 0);
            }
            __builtin_amdgcn_s_setprio(0);
        }
    };

    // named double buffer (static indexing, rule #20); loads 1 pair ahead.
    // pp=0..15 computes pairs 2pp (pa0) and 2pp+1 (pa1): pairs 0..31, once each.
    v4i pa0[4], pw0[2], pa1[4], pw1[2];
    loadPair(pa0, pw0, 0);
#pragma unroll 1
    for (int pp = 0; pp < NPAIR / 2; ++pp) {
        loadPair(pa1, pw1, 2 * pp + 1);
        computePair(pa0, pw0);
        if (pp < NPAIR / 2 - 1) loadPair(pa0, pw0, 2 * pp + 2);
        computePair(pa1, pw1);
    }

    // Epilogue: out = 4*acc - 2*rsA[row] - 2*rsW[col] + K + bias
    const int cl = lane & 31;
    const int r0 = (lane >> 5) * 4;
    const int m0 = by * BM;
    const int n0 = bx * BN;
#pragma unroll
    for (int mt = 0; mt < 4; ++mt) {
#pragma unroll
        for (int nt = 0; nt < 2; ++nt) {
            const int col = n0 + (wc * 2 + nt) * 32 + cl;
            const float bv = bias[col];
            const int rw2 = 2 * wrs[nt];     // lane's own W row == its col
#pragma unroll
            for (int rg = 0; rg < 16; ++rg) {
                const int rig = r0 + (rg & 3) + 8 * (rg >> 2);   // row in group
                const int ra  = __shfl(ars[mt], rig);            // held by lane rig
                const int v   = 4 * acc[mt][nt][rg] - 2 * ra - rw2 + KDIM;
                const int row = m0 + (wr * 4 + mt) * 32 + rig;
                out[(size_t)row * OUTF + col] = (float)v + bv;
            }
        }
    }
}

extern "C" void kernel_launch(void* const* d_in, const int* in_sizes, int n_in,
                              void* d_out, int out_size, void* d_ws, size_t ws_size,
                              hipStream_t stream) {
    const int*   a_packed = (const int*)d_in[0];    // [8192, 512] int32, low byte
    const int*   w_packed = (const int*)d_in[1];    // [4096, 512] int32, low byte
    const float* bias     = (const float*)d_in[2];  // [4096]
    float*       out      = (float*)d_out;          // [8192, 4096]

    uint4* Ab = (uint4*)d_ws;                       // 4 MiB dense bits, pair-major
    uint4* Wb = (uint4*)((char*)d_ws + (size_t)BATCH * 512);  // +4 MiB -> 2 MiB

    const int total = (BATCH + OUTF) * NPAIR;       // 393,216 threads
    bitpack<<<total / 256, 256, 0, stream>>>(a_packed, w_packed, Ab, Wb);

    dim3 grid(OUTF / BN, BATCH / BM);               // (16, 32)
    bitgemm_fused<<<grid, 512, 0, stream>>>((const v4i*)Ab, (const v4i*)Wb,
                                            bias, out);
}

// Round 6
// 257.384 us; speedup vs baseline: 1.0899x; 1.0069x over previous
//
#include <hip/hip_runtime.h>
#include <stdint.h>

// BitLinear via i8 MFMA, round 9: popcount-identity fused GEMM, no LDS,
// expansion VALU pinned to 3 full-rate ops/nibble via inline asm.
//
// Post-mortem r8: FETCH 147->19 MB, LDS 0, absmax 0 -- memory solved. But
// VALUBusy 70% vs MfmaUtil 40%: in-register bit->byte expansion is the
// binding pipe (~930 VALU-inst/wave/pair measured vs ~390 expected; codegen
// emitted extraction chains + likely quarter-rate v_mul_lo_u32).
//
// r9 change: per nibble exactly 3 guaranteed full-rate VALU:
//     v_bfe_u32     n, word, (hl16+4j), 4     ; 1-op variable extract
//     v_mul_u32_u24 t, 0x204081, n            ; full-rate (operands < 2^24)
//     v_and_b32     r, 0x01010101, t          ; bit i -> byte i of {0,1}
// Mapping identical to r8: byte 4j+i of window c == k-bit 32c+hl16+4j+i,
// same for A and W -> dot product unchanged -> absmax 0 carries over.
//
// identity: for bits a,w in {0,1}:  sum (2a-1)(2w-1)
//         = 4*sum(a&w) - 2*rowsum(a) - 2*rowsum(w) + K
// Output mapping (32x32 i8 MFMA C/D, HW-verified):
//   col = lane&31, row = (reg&3) + 8*(reg>>2) + 4*(lane>>5).

typedef int v4i  __attribute__((ext_vector_type(4)));
typedef int v16i __attribute__((ext_vector_type(16)));

#define BATCH 8192
#define OUTF  4096
#define KDIM  4096
#define BM    256
#define BN    256
#define NPAIR 32   // 1 pair = 128 k-bits = 16 B/row = 4 K=32 MFMA windows

// ---------------- k1: repack to dense bits, pair-major --------------------
__device__ __forceinline__ uint32_t pack4(int4 q) {
    // each int holds one byte (0..255) of packed bits, LSB-first along k
    return (uint32_t)q.x | ((uint32_t)q.y << 8) |
           ((uint32_t)q.z << 16) | ((uint32_t)q.w << 24);
}

__global__ __launch_bounds__(256) void bitpack(const int* __restrict__ ap,
                                               const int* __restrict__ wp,
                                               uint4* __restrict__ Ab,
                                               uint4* __restrict__ Wb) {
    int t = blockIdx.x * 256 + threadIdx.x;
    const int* src;
    uint4* dst;
    if (t < BATCH * NPAIR) {                 // A: 262144 threads
        const int p = t >> 13, m = t & 8191;
        src = ap + m * 512 + p * 16;
        dst = Ab + (p * BATCH + m);
    } else {                                 // W: 131072 threads
        const int u = t - BATCH * NPAIR;
        const int p = u >> 12, n = u & 4095;
        src = wp + n * 512 + p * 16;
        dst = Wb + (p * OUTF + n);
    }
    const int4* s4 = (const int4*)src;       // 64 B contiguous read
    int4 q0 = s4[0], q1 = s4[1], q2 = s4[2], q3 = s4[3];
    uint4 o;
    o.x = pack4(q0); o.y = pack4(q1); o.z = pack4(q2); o.w = pack4(q3);
    *dst = o;                                // 16 B coalesced write
}

// ---------------- k2: fused expand + i8 MFMA GEMM, no LDS ------------------
// nibble at bit-offset `off` of `w`  ->  4 bytes of {0,1} (bit i -> byte i).
// Pinned to 3 full-rate VALU ops; non-volatile asm stays schedulable/CSE-able.
__device__ __forceinline__ int nib_spread(int w, int off) {
    int n, t, r;
    asm("v_bfe_u32 %0, %1, %2, 4" : "=v"(n) : "v"(w), "v"(off));
    asm("v_mul_u32_u24 %0, 0x204081, %1" : "=v"(t) : "v"(n));
    asm("v_and_b32 %0, 0x01010101, %1" : "=v"(r) : "v"(t));
    return r;
}

__global__ __launch_bounds__(512, 2) void bitgemm_fused(const v4i* __restrict__ Ab,
                                                        const v4i* __restrict__ Wb,
                                                        const float* __restrict__ bias,
                                                        float* __restrict__ out) {
    const int tid  = threadIdx.x;
    const int lane = tid & 63;
    const int w    = __builtin_amdgcn_readfirstlane(tid >> 6);  // 0..7
    const int wr   = w >> 2;        // wave M row: 0..1 (128 rows)
    const int wc   = w & 3;         // wave N col: 0..3 (64 cols)
    const int rl   = lane & 31;
    const int hl16 = (lane >> 5) * 16;  // which 16-bit half this lane consumes
    const int bx   = blockIdx.x;    // N: 16
    const int by   = blockIdx.y;    // M: 32

    // nibble bit-offsets for this lane's half (VGPR operands for v_bfe)
    const int of0 = hl16, of1 = hl16 + 4, of2 = hl16 + 8, of3 = hl16 + 12;

    // lane's packed rows (pair-major panels)
    const int rowA0 = by * 256 + wr * 128 + rl;   // + mt*32
    const int rowW0 = bx * 256 + wc * 64 + rl;    // + nt*32

    v16i acc[4][2];
#pragma unroll
    for (int mt = 0; mt < 4; ++mt)
#pragma unroll
        for (int nt = 0; nt < 2; ++nt)
#pragma unroll
            for (int rg = 0; rg < 16; ++rg) acc[mt][nt][rg] = 0;

    int ars[4] = {0, 0, 0, 0};   // rowsum(A bits) for lane's 4 A rows
    int wrs[2] = {0, 0};         // rowsum(W bits) for lane's 2 W rows

    auto loadPair = [&](v4i (&pa)[4], v4i (&pw)[2], int p) {
#pragma unroll
        for (int mt = 0; mt < 4; ++mt)
            pa[mt] = Ab[(size_t)p * BATCH + rowA0 + mt * 32];
#pragma unroll
        for (int nt = 0; nt < 2; ++nt)
            pw[nt] = Wb[(size_t)p * OUTF + rowW0 + nt * 32];
    };

    auto expand_slot = [&](int word) -> v4i {
        v4i r;
        r[0] = nib_spread(word, of0);
        r[1] = nib_spread(word, of1);
        r[2] = nib_spread(word, of2);
        r[3] = nib_spread(word, of3);
        return r;
    };

    auto computePair = [&](const v4i (&pa)[4], const v4i (&pw)[2]) {
        // rowsums (v_bcnt_u32_b32 has a fused addend; compiler chains these)
#pragma unroll
        for (int mt = 0; mt < 4; ++mt)
            ars[mt] += __popc((uint32_t)pa[mt][0]) + __popc((uint32_t)pa[mt][1]) +
                       __popc((uint32_t)pa[mt][2]) + __popc((uint32_t)pa[mt][3]);
#pragma unroll
        for (int nt = 0; nt < 2; ++nt)
            wrs[nt] += __popc((uint32_t)pw[nt][0]) + __popc((uint32_t)pw[nt][1]) +
                       __popc((uint32_t)pw[nt][2]) + __popc((uint32_t)pw[nt][3]);
        // 4 x K=32 MFMA windows per pair: word c, this lane's 16-bit half
#pragma unroll
        for (int c = 0; c < 4; ++c) {
            v4i av[4], wv[2];
#pragma unroll
            for (int mt = 0; mt < 4; ++mt) av[mt] = expand_slot(pa[mt][c]);
#pragma unroll
            for (int nt = 0; nt < 2; ++nt) wv[nt] = expand_slot(pw[nt][c]);
            __builtin_amdgcn_s_setprio(1);
#pragma unroll
            for (int mt = 0; mt < 4; ++mt) {
                acc[mt][0] = __builtin_amdgcn_mfma_i32_32x32x32_i8(av[mt], wv[0],
                                                                   acc[mt][0], 0, 0, 0);
                acc[mt][1] = __builtin_amdgcn_mfma_i32_32x32x32_i8(av[mt], wv[1],
                                                                   acc[mt][1], 0, 0, 0);
            }
            __builtin_amdgcn_s_setprio(0);
        }
    };

    // named double buffer (static indexing, rule #20); loads 1 pair ahead.
    // pp=0..15 computes pairs 2pp (pa0) and 2pp+1 (pa1): pairs 0..31, once each.
    v4i pa0[4], pw0[2], pa1[4], pw1[2];
    loadPair(pa0, pw0, 0);
#pragma unroll 1
    for (int pp = 0; pp < NPAIR / 2; ++pp) {
        loadPair(pa1, pw1, 2 * pp + 1);
        computePair(pa0, pw0);
        if (pp < NPAIR / 2 - 1) loadPair(pa0, pw0, 2 * pp + 2);
        computePair(pa1, pw1);
    }

    // Epilogue: out = 4*acc - 2*rsA[row] - 2*rsW[col] + K + bias
    const int cl = lane & 31;
    const int r0 = (lane >> 5) * 4;
    const int m0 = by * BM;
    const int n0 = bx * BN;
#pragma unroll
    for (int mt = 0; mt < 4; ++mt) {
#pragma unroll
        for (int nt = 0; nt < 2; ++nt) {
            const int col = n0 + (wc * 2 + nt) * 32 + cl;
            const float bv = bias[col];
            const int rw2 = 2 * wrs[nt];     // lane's own W row == its col
#pragma unroll
            for (int rg = 0; rg < 16; ++rg) {
                const int rig = r0 + (rg & 3) + 8 * (rg >> 2);   // row in group
                const int ra  = __shfl(ars[mt], rig);            // held by lane rig
                const int v   = 4 * acc[mt][nt][rg] - 2 * ra - rw2 + KDIM;
                const int row = m0 + (wr * 4 + mt) * 32 + rig;
                out[(size_t)row * OUTF + col] = (float)v + bv;
            }
        }
    }
}

extern "C" void kernel_launch(void* const* d_in, const int* in_sizes, int n_in,
                              void* d_out, int out_size, void* d_ws, size_t ws_size,
                              hipStream_t stream) {
    const int*   a_packed = (const int*)d_in[0];    // [8192, 512] int32, low byte
    const int*   w_packed = (const int*)d_in[1];    // [4096, 512] int32, low byte
    const float* bias     = (const float*)d_in[2];  // [4096]
    float*       out      = (float*)d_out;          // [8192, 4096]

    uint4* Ab = (uint4*)d_ws;                       // 4 MiB dense bits, pair-major
    uint4* Wb = (uint4*)((char*)d_ws + (size_t)BATCH * 512);  // +4 MiB -> 2 MiB

    const int total = (BATCH + OUTF) * NPAIR;       // 393,216 threads
    bitpack<<<total / 256, 256, 0, stream>>>(a_packed, w_packed, Ab, Wb);

    dim3 grid(OUTF / BN, BATCH / BM);               // (16, 32)
    bitgemm_fused<<<grid, 512, 0, stream>>>((const v4i*)Ab, (const v4i*)Wb,
                                            bias, out);
}

// Round 7
// 250.340 us; speedup vs baseline: 1.1206x; 1.0281x over previous
//
#include <hip/hip_runtime.h>
#include <stdint.h>

// BitLinear via i8 MFMA, round 10: 4 waves/SIMD + perm-based expansion.
//
// Post-mortem r9: corrected accounting shows 32 MFMA/wave-pair = 1171 cyc vs
// ~600 cyc expansion VALU -> expansion was never the limiter. Four different
// memory designs (r4/r5/r8/r9) all sit at 142+-3 us with matrix pipe 40-44%:
// the invariant is 2 waves/SIMD (acc=128 VGPR) -> per-wave convoy stalls
// (expand latency, load waits) idle the matrix pipe and there's no 3rd/4th
// wave to fill it.
//
// r10 changes:
//  1. OCCUPANCY: wave-tile 64x64 (acc = 4 x v16i = 64 regs), 256-thr blocks,
//     block-tile 128x128, __launch_bounds__(256,4) -> <=128 regs/wave ->
//     4 waves/SIMD (16/CU), 2x the MFMA issue parallelism.
//  2. EXPANSION: v_perm_b32 byte-replicate + AND-in-place. W is stored
//     BYTE-BIT-REVERSED by k1, so for every byte position A-weight(2^j) x
//     W-weight(2^(7-j)) -- after >>1 on the bit-7 ints (signed-i8 safety)
//     every product is exactly 2^6. acc = 64*sum(a&w); 4*sum = acc>>4.
//     8 VALU per v4i (2 perm + 4 and + 2 shift) vs 12 before.
//  3. Rowsum popcounts moved to k1 (atomicAdd into rsA/rsW); hot loop has
//     ZERO popcounts; epilogue loads rowsums (L1-resident).
//
// identity: sum(2a-1)(2w-1) = 4*sum(a&w) - 2*rowsum(a) - 2*rowsum(w) + K
// Output mapping (32x32 i8 MFMA C/D, HW-verified):
//   col = lane&31, row = (reg&3) + 8*(reg>>2) + 4*(lane>>5).

typedef int v4i  __attribute__((ext_vector_type(4)));
typedef int v16i __attribute__((ext_vector_type(16)));

#define BATCH 8192
#define OUTF  4096
#define KDIM  4096
#define NPAIR 32   // 1 pair = 128 k-bits = 16 B/row = 4 K=32 MFMA windows

// ---------------- k1: repack to dense bits + rowsums ----------------------
__device__ __forceinline__ uint32_t pack4(int4 q) {
    // each int holds one byte (0..255) of packed bits, LSB-first along k
    return (uint32_t)q.x | ((uint32_t)q.y << 8) |
           ((uint32_t)q.z << 16) | ((uint32_t)q.w << 24);
}
// byte-wise bit reverse: brev flips all 32 bits (byte j bit b -> byte 3-j
// bit 7-b), bswap restores byte order -> byte j bit 7-b.
__device__ __forceinline__ uint32_t bytebitrev(uint32_t x) {
    return __builtin_bswap32(__brev(x));
}

__global__ __launch_bounds__(256) void bitpack(const int* __restrict__ ap,
                                               const int* __restrict__ wp,
                                               uint4* __restrict__ Ab,
                                               uint4* __restrict__ Wb,
                                               int* __restrict__ rsA,
                                               int* __restrict__ rsW) {
    int t = blockIdx.x * 256 + threadIdx.x;
    const int* src;
    uint4* dst;
    int* rs;
    bool isW;
    if (t < BATCH * NPAIR) {                 // A: 262144 threads
        const int p = t >> 13, m = t & 8191;
        src = ap + m * 512 + p * 16;
        dst = Ab + (p * BATCH + m);
        rs  = rsA + m;
        isW = false;
    } else {                                 // W: 131072 threads
        const int u = t - BATCH * NPAIR;
        const int p = u >> 12, n = u & 4095;
        src = wp + n * 512 + p * 16;
        dst = Wb + (p * OUTF + n);
        rs  = rsW + n;
        isW = true;
    }
    const int4* s4 = (const int4*)src;       // 64 B contiguous read
    int4 q0 = s4[0], q1 = s4[1], q2 = s4[2], q3 = s4[3];
    uint4 o;
    o.x = pack4(q0); o.y = pack4(q1); o.z = pack4(q2); o.w = pack4(q3);
    const int pc = __popc(o.x) + __popc(o.y) + __popc(o.z) + __popc(o.w);
    atomicAdd(rs, pc);
    if (isW) {                               // bit-reverse each byte for the
        o.x = bytebitrev(o.x); o.y = bytebitrev(o.y);   // weight-pairing trick
        o.z = bytebitrev(o.z); o.w = bytebitrev(o.w);
    }
    *dst = o;                                // 16 B coalesced write
}

// ---------------- k2: fused expand + i8 MFMA GEMM, no LDS ------------------
// A expansion: byte value = a_bit << j  (weights 1,2,4,8 / 8,16,32,64)
// W expansion (bit-reversed storage): byte value = w_bit << (6-j) etc.
// Every A-byte x W-byte product = 2^6; all bytes <= 0x40 (signed-i8 safe).
__device__ __forceinline__ v4i expandA(uint32_t w, uint32_t s0, uint32_t s1) {
    uint32_t p0 = __builtin_amdgcn_perm(w, w, s0);   // [B,B,B,B], B = byte 2h
    uint32_t p1 = __builtin_amdgcn_perm(w, w, s1);   // byte 2h+1
    v4i r;
    r[0] = (int)(p0 & 0x08040201u);          // k 0..3  : weights 1,2,4,8
    r[1] = (int)((p0 & 0x80402010u) >> 1);   // k 4..7  : weights 8,16,32,64
    r[2] = (int)(p1 & 0x08040201u);          // k 8..11
    r[3] = (int)((p1 & 0x80402010u) >> 1);   // k 12..15
    return r;
}
__device__ __forceinline__ v4i expandW(uint32_t w, uint32_t s0, uint32_t s1) {
    uint32_t p0 = __builtin_amdgcn_perm(w, w, s0);
    uint32_t p1 = __builtin_amdgcn_perm(w, w, s1);
    v4i r;
    r[0] = (int)((p0 & 0x10204080u) >> 1);   // k 0..3  : weights 64,32,16,8
    r[1] = (int)(p0 & 0x01020408u);          // k 4..7  : weights 8,4,2,1
    r[2] = (int)((p1 & 0x10204080u) >> 1);   // k 8..11
    r[3] = (int)(p1 & 0x01020408u);          // k 12..15
    return r;
}

__global__ __launch_bounds__(256, 4) void bitgemm_fused(const v4i* __restrict__ Ab,
                                                        const v4i* __restrict__ Wb,
                                                        const int* __restrict__ rsA,
                                                        const int* __restrict__ rsW,
                                                        const float* __restrict__ bias,
                                                        float* __restrict__ out) {
    const int tid  = threadIdx.x;
    const int lane = tid & 63;
    const int w    = __builtin_amdgcn_readfirstlane(tid >> 6);  // 0..3
    const int wr   = w >> 1;        // wave M row: 0..1 (64 rows each)
    const int wc   = w & 1;         // wave N col: 0..1 (64 cols each)
    const int rl   = lane & 31;
    const int h    = lane >> 5;     // 16-bit half this lane consumes
    const int bx   = blockIdx.x;    // N: 32 blocks
    const int by   = blockIdx.y;    // M: 64 blocks

    const uint32_t s0 = h ? 0x02020202u : 0x00000000u;  // perm sel: byte 2h
    const uint32_t s1 = s0 + 0x01010101u;               // byte 2h+1

    // lane's packed rows (pair-major panels)
    const int rowA0 = by * 128 + wr * 64 + rl;   // + mt*32
    const int rowW0 = bx * 128 + wc * 64 + rl;   // + nt*32

    v16i acc[2][2];
#pragma unroll
    for (int mt = 0; mt < 2; ++mt)
#pragma unroll
        for (int nt = 0; nt < 2; ++nt)
#pragma unroll
            for (int rg = 0; rg < 16; ++rg) acc[mt][nt][rg] = 0;

    auto loadPair = [&](v4i (&pa)[2], v4i (&pw)[2], int p) {
#pragma unroll
        for (int mt = 0; mt < 2; ++mt)
            pa[mt] = Ab[(size_t)p * BATCH + rowA0 + mt * 32];
#pragma unroll
        for (int nt = 0; nt < 2; ++nt)
            pw[nt] = Wb[(size_t)p * OUTF + rowW0 + nt * 32];
    };

    auto computePair = [&](const v4i (&pa)[2], const v4i (&pw)[2]) {
#pragma unroll
        for (int c = 0; c < 4; ++c) {
            v4i a0 = expandA((uint32_t)pa[0][c], s0, s1);
            v4i a1 = expandA((uint32_t)pa[1][c], s0, s1);
            v4i w0 = expandW((uint32_t)pw[0][c], s0, s1);
            v4i w1 = expandW((uint32_t)pw[1][c], s0, s1);
            __builtin_amdgcn_s_setprio(1);
            acc[0][0] = __builtin_amdgcn_mfma_i32_32x32x32_i8(a0, w0, acc[0][0], 0, 0, 0);
            acc[0][1] = __builtin_amdgcn_mfma_i32_32x32x32_i8(a0, w1, acc[0][1], 0, 0, 0);
            acc[1][0] = __builtin_amdgcn_mfma_i32_32x32x32_i8(a1, w0, acc[1][0], 0, 0, 0);
            acc[1][1] = __builtin_amdgcn_mfma_i32_32x32x32_i8(a1, w1, acc[1][1], 0, 0, 0);
            __builtin_amdgcn_s_setprio(0);
        }
    };

    // named double buffer (static indexing); loads 1 pair ahead.
    v4i pa0[2], pw0[2], pa1[2], pw1[2];
    loadPair(pa0, pw0, 0);
#pragma unroll 1
    for (int pp = 0; pp < NPAIR / 2; ++pp) {
        loadPair(pa1, pw1, 2 * pp + 1);
        computePair(pa0, pw0);
        if (pp < NPAIR / 2 - 1) loadPair(pa0, pw0, 2 * pp + 2);
        computePair(pa1, pw1);
    }

    // Epilogue: out = (acc>>4) - 2*rsA[row] - 2*rsW[col] + K + bias
    // (acc = 64 * sum(a&w); 4*sum = acc>>4)
    const int cl = lane & 31;
    const int r0 = (lane >> 5) * 4;
    const int m0 = by * 128 + wr * 64;
    const int n0 = bx * 128 + wc * 64;
#pragma unroll
    for (int mt = 0; mt < 2; ++mt) {
#pragma unroll
        for (int nt = 0; nt < 2; ++nt) {
            const int col = n0 + nt * 32 + cl;
            const float bv = bias[col];
            const int rw2 = 2 * rsW[col];
#pragma unroll
            for (int rg = 0; rg < 16; ++rg) {
                const int rig = r0 + (rg & 3) + 8 * (rg >> 2);
                const int row = m0 + mt * 32 + rig;
                const int v = (acc[mt][nt][rg] >> 4) - 2 * rsA[row] - rw2 + KDIM;
                out[(size_t)row * OUTF + col] = (float)v + bv;
            }
        }
    }
}

extern "C" void kernel_launch(void* const* d_in, const int* in_sizes, int n_in,
                              void* d_out, int out_size, void* d_ws, size_t ws_size,
                              hipStream_t stream) {
    const int*   a_packed = (const int*)d_in[0];    // [8192, 512] int32, low byte
    const int*   w_packed = (const int*)d_in[1];    // [4096, 512] int32, low byte
    const float* bias     = (const float*)d_in[2];  // [4096]
    float*       out      = (float*)d_out;          // [8192, 4096]

    uint4* Ab = (uint4*)d_ws;                                   // 4 MiB bits
    uint4* Wb = (uint4*)((char*)d_ws + (size_t)BATCH * 512);    // 2 MiB bits
    int*   rsA = (int*)((char*)d_ws + 6u * 1024 * 1024);        // 32 KiB
    int*   rsW = rsA + BATCH;                                   // 16 KiB

    hipMemsetAsync(rsA, 0, (BATCH + OUTF) * sizeof(int), stream);

    const int total = (BATCH + OUTF) * NPAIR;       // 393,216 threads
    bitpack<<<total / 256, 256, 0, stream>>>(a_packed, w_packed, Ab, Wb, rsA, rsW);

    dim3 grid(OUTF / 128, BATCH / 128);             // (32, 64) = 2048 blocks
    bitgemm_fused<<<grid, 256, 0, stream>>>((const v4i*)Ab, (const v4i*)Wb,
                                            rsA, rsW, bias, out);
}